// Round 7
// baseline (122.005 us; speedup 1.0000x reference)
//
#include <hip/hip_runtime.h>
#include <hip/hip_bf16.h>

// Problem constants (fixed by reference):
//   B=16, L=512, D=C=F=256, K=3, M=2048, EPS=1e-5
// Float tensors f32; target int32. Convs on bf16 MFMA (f32 accum).
#define Bn 16
#define Ln 512
#define Cn 256
#define Fn 256
#define Kn 3
#define Mn 2048

#define NKSTEP 24        // 768 / 32
#define MT 32            // L-rows per conv block -> 256 conv blocks (1/CU)
#define XS_PS 264        // LDS A-slab row stride (bf16 units); 528 B = 33*16
#define NCONVBLK 256
#define NGATH_HALF 2048  // gather blocks per conv kernel (512 thr each; 2*2048*512 = 2097152 e4)

typedef __attribute__((ext_vector_type(8))) short short8;
typedef __attribute__((ext_vector_type(4))) float f32x4;

static __device__ __forceinline__ unsigned short f2bf(float f) {
    unsigned int u = __float_as_uint(f);
    return (unsigned short)((u + 0x7fff + ((u >> 16) & 1)) >> 16);   // RNE
}

// pack element i of w (F,C,K) f32 into MFMA B-frag order (layout verified r3..r6):
// bp[((s*16+nt)*64+lane)*8+j] = w[f=nt*16+(lane&15)][d][k], kappa=k*256+d=s*32+(lane>>4)*8+j
static __device__ __forceinline__ void pack_one(const float* __restrict__ w,
                                                unsigned short* __restrict__ bp,
                                                int i) {
    int j    = i & 7;
    int lane = (i >> 3) & 63;
    int nt   = (i >> 9) & 15;
    int s    = i >> 13;
    int kap = s * 32 + ((lane >> 4) * 8) + j;
    int k = kap >> 8;
    int d = kap & 255;
    int f = nt * 16 + (lane & 15);
    bp[i] = f2bf(w[(f * Cn + d) * Kn + k]);
}

// ---------- K1: pack w1+w2 (blocks 0..767) + duration scan (blocks 768..783) ----------
__global__ __launch_bounds__(512) void pack_scan(
    const float* __restrict__ w1, const float* __restrict__ w2,
    unsigned short* __restrict__ bp1, unsigned short* __restrict__ bp2,
    const int* __restrict__ target, int* __restrict__ map)
{
    __shared__ int ss[Ln];
    const int blk = blockIdx.x;
    const int t = threadIdx.x;
    if (blk < 768) {
        int i = blk * 512 + t;
        const float* w = w1;
        unsigned short* bp = bp1;
        if (i >= Fn * Cn * Kn) { i -= Fn * Cn * Kn; w = w2; bp = bp2; }
        pack_one(w, bp, i);
        return;
    }
    int b = blk - 768;
    int v = target[b * Ln + t];
    ss[t] = v;
    __syncthreads();
    for (int off = 1; off < Ln; off <<= 1) {
        int add = (t >= off) ? ss[t - off] : 0;
        __syncthreads();
        ss[t] += add;
        __syncthreads();
    }
    int cs    = ss[t];          // inclusive cumsum
    int prev  = cs - v;
    int total = ss[Ln - 1];
    for (int m = prev; m < cs; ++m) map[b * Mn + m] = t;
    for (int m = total + t; m < Mn; m += Ln) map[b * Mn + m] = -1;
}

// ---------- fused conv1d(K=3,SAME) via MFMA + bias + LayerNorm + ReLU ----------
// Conv blocks [0,256): 32 L-rows of one batch; 512 threads = 8 waves (2 waves/SIMD).
// Wave wv owns n-tiles {2wv, 2wv+1} (B read ONCE per block) and both m-tiles.
// A-frag (16x16x32): A[m=lane&15][k=(lane>>4)*8+j]; C/D: col=lane&15, row=(lane>>4)*4+reg.
// K-loop ring uses explicitly NAMED registers (macros, literal slots) — spill-proof.
// WITH_AUX: blocks >= 256 do a slice of the length-regulate gather.
template <bool IS_F32_IN, bool DO_LINEAR, bool WITH_AUX>
__global__ __launch_bounds__(512) void conv_mfma(
    const void* __restrict__ in_,               // (B,L,C) f32 or bf16
    const unsigned short* __restrict__ bp,      // packed weights (bf16 frag order)
    const float* __restrict__ bias,             // (F)
    const float* __restrict__ gamma,            // (F)
    const float* __restrict__ beta,             // (F)
    const float* __restrict__ lw,               // (F)  [DO_LINEAR]
    const float* __restrict__ lb,               // (1)  [DO_LINEAR]
    unsigned short* __restrict__ hout,          // bf16 (B,L,F) [!DO_LINEAR]
    float* __restrict__ dup,                    // (B,L)        [DO_LINEAR]
    const float* __restrict__ gx,               // (B,L,C) f32  [WITH_AUX]
    const int* __restrict__ gmap,               // (B,M)        [WITH_AUX]
    float* __restrict__ gout,                   // (B,M,C)      [WITH_AUX]
    int gofs)                                   // gather e4 offset [WITH_AUX]
{
    __shared__ __align__(16) unsigned short xs[(MT + 2) * XS_PS];  // ~18 KB
    __shared__ float2 red[MT][8];                                  // 2 KB
    __shared__ float  red2[MT][8];                                 // 1 KB

    const int t = threadIdx.x;

    if (WITH_AUX && blockIdx.x >= NCONVBLK) {
        // ---- length-regulate gather slice: out[b,m,:] = (map>=0) ? x[b,map,:] : 0 ----
        int e4 = (blockIdx.x - NCONVBLK) * 512 + t + gofs;   // float4 index
        int d4 = e4 & 63;
        int bm = e4 >> 6;
        int b  = bm >> 11;
        int l  = gmap[bm];
        float4 val = make_float4(0.f, 0.f, 0.f, 0.f);
        if (l >= 0) val = *((const float4*)(gx + (size_t)(b * Ln + l) * Cn) + d4);
        ((float4*)gout)[e4] = val;
        return;
    }

    const int b  = blockIdx.x >> 4;          // 16 l-tiles per batch
    const int l0 = (blockIdx.x & 15) * MT;

    // ---- stage input rows [l0-1, l0+32], zero-padded, as bf16 ----
    if (IS_F32_IN) {
        const float* in = (const float*)in_;
        for (int idx = t; idx < (MT + 2) * 64; idx += 512) {   // 64 float4 per row
            int row = idx >> 6;
            int c4  = (idx & 63) * 4;
            int l = l0 + row - 1;
            float4 v = make_float4(0.f, 0.f, 0.f, 0.f);
            if (l >= 0 && l < Ln) v = *(const float4*)&in[((size_t)b * Ln + l) * Cn + c4];
            unsigned int lo = (unsigned int)f2bf(v.x) | ((unsigned int)f2bf(v.y) << 16);
            unsigned int hi = (unsigned int)f2bf(v.z) | ((unsigned int)f2bf(v.w) << 16);
            *(uint2*)&xs[row * XS_PS + c4] = make_uint2(lo, hi);
        }
    } else {
        const unsigned short* in = (const unsigned short*)in_;
        for (int idx = t; idx < (MT + 2) * 32; idx += 512) {   // 32 x (8 bf16) per row
            int row = idx >> 5;
            int c8  = (idx & 31) * 8;
            int l = l0 + row - 1;
            uint4 v = make_uint4(0u, 0u, 0u, 0u);
            if (l >= 0 && l < Ln) v = *(const uint4*)&in[((size_t)b * Ln + l) * Cn + c8];
            *(uint4*)&xs[row * XS_PS + c8] = v;
        }
    }
    __syncthreads();

    const int lane = t & 63;
    const int wv   = t >> 6;      // 8 waves; wave covers cols wv*32 .. wv*32+31
    const int mrow = lane & 15;
    const int q    = lane >> 4;

    f32x4 acc00 = {}, acc01 = {}, acc10 = {}, acc11 = {};   // [mt][nt-half]
    short8 a0_0, a1_0, b0_0, b1_0;   // slot 0 (explicit names -> no scratch)
    short8 a0_1, a1_1, b0_1, b1_1;   // slot 1

#define LOADB(B0, B1, s_) { \
    const unsigned short* p_ = bp + (size_t)((((s_) * 16) + wv * 2) * 64 + lane) * 8; \
    B0 = *(const short8*)p_; \
    B1 = *(const short8*)(p_ + 512); }
#define LOADA(A0, A1, s_) { \
    const int k_ = (s_) >> 3; \
    const int dc_ = ((s_) & 7) * 32 + q * 8; \
    A0 = *(const short8*)&xs[(mrow + k_) * XS_PS + dc_]; \
    A1 = *(const short8*)&xs[(16 + mrow + k_) * XS_PS + dc_]; }
#define DOMFMA(A0, A1, B0, B1) { \
    acc00 = __builtin_amdgcn_mfma_f32_16x16x32_bf16(A0, B0, acc00, 0, 0, 0); \
    acc01 = __builtin_amdgcn_mfma_f32_16x16x32_bf16(A0, B1, acc01, 0, 0, 0); \
    acc10 = __builtin_amdgcn_mfma_f32_16x16x32_bf16(A1, B0, acc10, 0, 0, 0); \
    acc11 = __builtin_amdgcn_mfma_f32_16x16x32_bf16(A1, B1, acc11, 0, 0, 0); }

    LOADB(b0_0, b1_0, 0) LOADA(a0_0, a1_0, 0)
    LOADB(b0_1, b1_1, 1) LOADA(a0_1, a1_1, 1)

    #pragma unroll
    for (int s = 0; s < NKSTEP; s += 2) {
        DOMFMA(a0_0, a1_0, b0_0, b1_0)
        if (s + 2 < NKSTEP) { LOADB(b0_0, b1_0, s + 2) LOADA(a0_0, a1_0, s + 2) }
        DOMFMA(a0_1, a1_1, b0_1, b1_1)
        if (s + 3 < NKSTEP) { LOADB(b0_1, b1_1, s + 3) LOADA(a0_1, a1_1, s + 3) }
    }
#undef LOADB
#undef LOADA
#undef DOMFMA

    // ---- epilogue: bias + LayerNorm from registers ----
    // lane covers cols c0 = wv*32+mrow (nt even) and c1 = wv*32+16+mrow (nt odd)
    const int c0 = wv * 32 + mrow;
    const int c1 = c0 + 16;
    float bias0 = bias[c0], bias1 = bias[c1];
    float g0 = gamma[c0], g1g = gamma[c1];
    float be0 = beta[c0], be1 = beta[c1];
    float lw0 = 0.f, lw1 = 0.f;
    if (DO_LINEAR) { lw0 = lw[c0]; lw1 = lw[c1]; }

    #pragma unroll
    for (int r = 0; r < 4; ++r) {
        acc00[r] += bias0; acc01[r] += bias1;
        acc10[r] += bias0; acc11[r] += bias1;
    }

    // per-row partials over this wave's 32 cols: in-lane pair, shuffle over 16 mrow lanes
    #pragma unroll
    for (int mt = 0; mt < 2; ++mt)
        #pragma unroll
        for (int r = 0; r < 4; ++r) {
            float v0 = mt ? acc10[r] : acc00[r];
            float v1 = mt ? acc11[r] : acc01[r];
            float s  = v0 + v1;
            float sq = v0 * v0 + v1 * v1;
            #pragma unroll
            for (int off = 1; off <= 8; off <<= 1) {
                s  += __shfl_xor(s,  off, 64);
                sq += __shfl_xor(sq, off, 64);
            }
            if (mrow == 0) red[mt * 16 + q * 4 + r][wv] = make_float2(s, sq);
        }
    __syncthreads();

    float muv[2][4], rsv[2][4];
    #pragma unroll
    for (int mt = 0; mt < 2; ++mt)
        #pragma unroll
        for (int r = 0; r < 4; ++r) {
            int row = mt * 16 + q * 4 + r;
            float s = 0.f, sq = 0.f;
            #pragma unroll
            for (int w = 0; w < 8; ++w) {
                float2 p = red[row][w];
                s += p.x; sq += p.y;
            }
            float mu  = s * (1.f / 256.f);
            float var = sq * (1.f / 256.f) - mu * mu;
            muv[mt][r] = mu;
            rsv[mt][r] = rsqrtf(var + 1e-5f);
        }

    if (!DO_LINEAR) {
        // store relu(LN(h)) as bf16
        #pragma unroll
        for (int mt = 0; mt < 2; ++mt)
            #pragma unroll
            for (int r = 0; r < 4; ++r) {
                float v0 = mt ? acc10[r] : acc00[r];
                float v1 = mt ? acc11[r] : acc01[r];
                int l = l0 + mt * 16 + q * 4 + r;
                size_t base = ((size_t)b * Ln + l) * Fn;
                float o0 = fmaxf((v0 - muv[mt][r]) * rsv[mt][r] * g0  + be0, 0.f);
                float o1 = fmaxf((v1 - muv[mt][r]) * rsv[mt][r] * g1g + be1, 0.f);
                hout[base + c0] = f2bf(o0);
                hout[base + c1] = f2bf(o1);
            }
    } else {
        // fused linear head: dup = relu( relu(LN(h)) . lw + lb )
        #pragma unroll
        for (int mt = 0; mt < 2; ++mt)
            #pragma unroll
            for (int r = 0; r < 4; ++r) {
                float v0 = mt ? acc10[r] : acc00[r];
                float v1 = mt ? acc11[r] : acc01[r];
                float o0 = fmaxf((v0 - muv[mt][r]) * rsv[mt][r] * g0  + be0, 0.f);
                float o1 = fmaxf((v1 - muv[mt][r]) * rsv[mt][r] * g1g + be1, 0.f);
                float dot = o0 * lw0 + o1 * lw1;
                #pragma unroll
                for (int off = 1; off <= 8; off <<= 1)
                    dot += __shfl_xor(dot, off, 64);
                if (mrow == 0) red2[mt * 16 + q * 4 + r][wv] = dot;
            }
        __syncthreads();
        if (t < MT) {
            float d = 0.f;
            #pragma unroll
            for (int w = 0; w < 8; ++w) d += red2[t][w];
            dup[b * Ln + l0 + t] = fmaxf(d + lb[0], 0.f);
        }
    }
}

extern "C" void kernel_launch(void* const* d_in, const int* in_sizes, int n_in,
                              void* d_out, int out_size, void* d_ws, size_t ws_size,
                              hipStream_t stream) {
    const float* x    = (const float*)d_in[0];
    const int*   targ = (const int*)d_in[1];
    // d_in[2] = mel_max_length (scalar) = 2048, hardcoded
    const float* c1w = (const float*)d_in[3];
    const float* c1b = (const float*)d_in[4];
    const float* g1  = (const float*)d_in[5];
    const float* be1 = (const float*)d_in[6];
    const float* c2w = (const float*)d_in[7];
    const float* c2b = (const float*)d_in[8];
    const float* g2  = (const float*)d_in[9];
    const float* be2 = (const float*)d_in[10];
    const float* lw  = (const float*)d_in[11];
    const float* lb  = (const float*)d_in[12];

    float* out     = (float*)d_out;                       // (B,M,C)
    float* out_dup = out + (size_t)Bn * Mn * Cn;          // (B,L)

    // workspace layout
    char* ws = (char*)d_ws;
    unsigned short* bp1 = (unsigned short*)ws;                       // 384 KiB
    unsigned short* bp2 = (unsigned short*)(ws + 393216);            // 384 KiB
    unsigned short* h1  = (unsigned short*)(ws + 2 * 393216);        // 4 MiB bf16
    int*            map = (int*)(ws + 2 * 393216 + 4194304);         // 128 KiB

    // K1: weight pack (768 blocks) + duration scan (16 blocks)
    pack_scan<<<784, 512, 0, stream>>>(c1w, c2w, bp1, bp2, targ, map);

    // K2: conv1 (blocks 0..255) + gather first half
    conv_mfma<true, false, true><<<NCONVBLK + NGATH_HALF, 512, 0, stream>>>(
        (const void*)x, bp1, c1b, g1, be1, nullptr, nullptr, h1, nullptr,
        x, map, out, 0);

    // K3: conv2 + fused linear head (blocks 0..255) + gather second half
    conv_mfma<false, true, true><<<NCONVBLK + NGATH_HALF, 512, 0, stream>>>(
        (const void*)h1, bp2, c2b, g2, be2, lw, lb, nullptr, out_dup,
        x, map, out, NGATH_HALF * 512);
}